// Round 13
// baseline (546.427 us; speedup 1.0000x reference)
//
#include <hip/hip_runtime.h>
#include <hip/hip_bf16.h>

#define NN 50000
#define EE 300000
#define BN_EPS 1e-5f
#define NFW 288            // NF row stride in fp16 elems
#define TWOPI_256 0.024543692606170259f  // 2*pi/256

typedef __attribute__((ext_vector_type(8))) _Float16 half8;
typedef __attribute__((ext_vector_type(2))) _Float16 half2v;
typedef __attribute__((ext_vector_type(4))) float f32x4;
#define MFMA16F __builtin_amdgcn_mfma_f32_16x16x32_f16

// ---- static device scratch ----
__device__ __align__(16) _Float16 g_NF[(size_t)NN * NFW];  // node rfft table, fp16
__device__ float g_Wle[256 * 256];                         // folded loop matrix, fp32
__device__ float g_C256[256];                              // Chat row 256 (Nyquist), fp32
// B operands pre-swizzled into MFMA fragment order: [ks][ntile][lane][8]
__device__ __align__(16) unsigned short g_FB[8 * 20 * 64 * 8];   // rfft matrix F
__device__ __align__(16) unsigned short g_CB[9 * 16 * 64 * 8];   // Chat
__device__ __align__(16) unsigned short g_WLEB[8 * 16 * 64 * 8]; // W_le
// dst counting-sort scratch
__device__ int g_hist[NN];
__device__ int g_off[NN + 1];
__device__ int g_cursor[NN];
__device__ int g_perm[EE];
__device__ int g_bsum[128];
__device__ int g_bbase[128];

__device__ __forceinline__ void atomAddF(float* p, float v) { unsafeAtomicAdd(p, v); }

__device__ __forceinline__ unsigned short f2hu(float x) {
    union { _Float16 f; unsigned short u; } c;
    c.f = (_Float16)x;
    return c.u;
}

// ---------------------------------------------------------------------------
// staged fp32 regs -> fp16 MFMA A-fragments in LDS (XOR-swizzled), 8 chunks.
// lane l of tile m, kstep ks holds A[m*16+(l&15)][32*ks+8*(l>>4)+e].
// ---------------------------------------------------------------------------
__device__ __forceinline__ void stage_write(char* A, const float4* stg, int t) {
#pragma unroll
    for (int q = 0; q < 8; ++q) {
        int idx = q * 512 + t;
        int row = idx >> 6, c4 = idx & 63;
        union { _Float16 f[4]; ushort4 u; } r;
        r.f[0] = (_Float16)stg[q].x; r.f[1] = (_Float16)stg[q].y;
        r.f[2] = (_Float16)stg[q].z; r.f[3] = (_Float16)stg[q].w;
        int ks = c4 >> 3;
        int off = ((row >> 4) * 8 + ks) * 1024 +
                  ((((((c4 >> 1) & 3) << 4) | (row & 15)) * 16) ^ (ks << 4)) +
                  (c4 & 1) * 8;
        *(ushort4*)(A + off) = r.u;
    }
}

// full-wave sum of v across 64 lanes
__device__ __forceinline__ float waveSum(float v) {
#pragma unroll
    for (int d = 1; d < 64; d <<= 1) v += __shfl_xor(v, d);
    return v;
}

// ---------------------------------------------------------------------------
// dst counting sort: hist -> 2-level exclusive scan -> permutation
// ---------------------------------------------------------------------------
__global__ __launch_bounds__(512) void hist_kernel(const int* __restrict__ dst, int E) {
    int e = blockIdx.x * 512 + threadIdx.x;
    if (e < E) atomicAdd(&g_hist[dst[e]], 1);
}

__global__ __launch_bounds__(512) void scanA_kernel(int N) {
    __shared__ int arr[512];
    int t = threadIdx.x, b = blockIdx.x * 512 + t;
    int cnt = (b < N) ? g_hist[b] : 0;
    arr[t] = cnt;
    __syncthreads();
#pragma unroll
    for (int off = 1; off < 512; off <<= 1) {
        int v = (t >= off) ? arr[t - off] : 0;
        __syncthreads();
        arr[t] += v;
        __syncthreads();
    }
    if (b < N) g_off[b] = arr[t] - cnt;
    if (t == 511) g_bsum[blockIdx.x] = arr[511];
}

__global__ __launch_bounds__(128) void scanB_kernel(int nblk) {
    __shared__ int arr[128];
    int t = threadIdx.x;
    int v0 = (t < nblk) ? g_bsum[t] : 0;
    arr[t] = v0;
    __syncthreads();
#pragma unroll
    for (int off = 1; off < 128; off <<= 1) {
        int v = (t >= off) ? arr[t - off] : 0;
        __syncthreads();
        arr[t] += v;
        __syncthreads();
    }
    if (t < nblk) g_bbase[t] = arr[t] - v0;
}

__global__ __launch_bounds__(512) void scanC_kernel(int N) {
    int b = blockIdx.x * 512 + threadIdx.x;
    if (b < N) {
        int v = g_off[b] + g_bbase[blockIdx.x];
        g_off[b] = v;
        g_cursor[b] = v;
        if (b == N - 1) g_off[N] = v + g_hist[b];
    }
}

__global__ __launch_bounds__(512) void perm_kernel(const int* __restrict__ dst, int E) {
    int e = blockIdx.x * 512 + threadIdx.x;
    if (e < E) {
        int pos = atomicAdd(&g_cursor[dst[e]], 1);
        g_perm[pos] = e;
    }
}

// ---------------------------------------------------------------------------
// K1: W_le[j][d] = sum_k loop_rel[(j+k)%256] * w_loop[k][d]
// ---------------------------------------------------------------------------
__global__ __launch_bounds__(256) void wle_kernel(
    const float* __restrict__ loop_rel, const float* __restrict__ w_loop,
    float* __restrict__ W_le) {
    __shared__ float lr[256];
    const int d = threadIdx.x, j = blockIdx.x;
    lr[d] = loop_rel[d];
    __syncthreads();
    float acc = 0.f;
#pragma unroll 4
    for (int k = 0; k < 256; ++k)
        acc = fmaf(lr[(j + k) & 255], w_loop[k * 256 + d], acc);
    W_le[j * 256 + d] = acc;
}

// ---------------------------------------------------------------------------
// pack F into B-fragment order, fp16
// ---------------------------------------------------------------------------
__global__ __launch_bounds__(512) void fb_pack() {
    int b = blockIdx.x, ks = b / 20, nt = b % 20;
    int t = threadIdx.x, lane = t >> 3, e = t & 7;
    int k = 32 * ks + 8 * (lane >> 4) + e;
    int r2 = nt * 16 + (lane & 15);
    float val = 0.f;
    if (r2 < 258) {
        int f = r2 >> 1;
        int m = (f * k) & 255;
        float s, c;
        sincosf((float)m * TWOPI_256, &s, &c);
        val = (r2 & 1) ? -s : c;
    }
    g_FB[((ks * 20 + nt) * 64 + lane) * 8 + e] = f2hu(val);
}

// ---------------------------------------------------------------------------
// pack Chat into B-fragment order, fp16; also emit fp32 row 256 -> g_C256.
// ---------------------------------------------------------------------------
__global__ __launch_bounds__(512) void cb_pack(const float* __restrict__ w_in) {
    __shared__ float ct[256], st[256];
    int t = threadIdx.x;
    if (t < 256) {
        float s, c;
        sincosf((float)t * TWOPI_256, &s, &c);
        ct[t] = c; st[t] = s;
    }
    __syncthreads();
    int b = blockIdx.x, ks = b / 16, nt = b % 16;
    int lane = t >> 3, e = t & 7;
    int kk = 32 * ks + 8 * (lane >> 4) + e;
    int d = nt * 16 + (lane & 15);
    float val = 0.f;
    if (kk < 258) {
        int f = kk >> 1;
        float cf = (f == 0 || f == 128) ? (1.f / 256.f) : (2.f / 256.f);
        const float* tab = (kk & 1) ? st : ct;
        float sgn = (kk & 1) ? -1.f : 1.f;
        float acc = 0.f;
        for (int k = 0; k < 256; ++k)
            acc = fmaf(tab[(f * k) & 255], w_in[k * 256 + d], acc);
        val = cf * sgn * acc;
    }
    if (kk == 256) g_C256[d] = val;   // Nyquist row, fp32
    g_CB[((ks * 16 + nt) * 64 + lane) * 8 + e] = f2hu(val);
}

// pack W_le into B-fragment order, fp16.
__global__ __launch_bounds__(512) void wleb_pack() {
    int b = blockIdx.x, ks = b / 16, nt = b % 16;
    int t = threadIdx.x, lane = t >> 3, e = t & 7;
    int k = 32 * ks + 8 * (lane >> 4) + e;
    int d = nt * 16 + (lane & 15);
    g_WLEB[((ks * 16 + nt) * 64 + lane) * 8 + e] = f2hu(g_Wle[k * 256 + d]);
}

// ---------------------------------------------------------------------------
// nfloop: per 64 node rows: NF = node @ F (cols 0..255 via MFMA; col 256 =
// alternating sum via wave-reduce during staging), d_out = node @ W_le + bias.
// ---------------------------------------------------------------------------
__global__ __launch_bounds__(512, 4) void nfloop_kernel(
    const float* __restrict__ node_ft, const float* __restrict__ w_bias,
    float* __restrict__ out, int N) {
    __shared__ char smem[32768];
    unsigned short* A = (unsigned short*)smem;
    const int t = threadIdx.x;
    const int wv = t >> 6;
    const long long r0 = (long long)blockIdx.x * 64;
    {
        float4 stg[8];
#pragma unroll
        for (int q = 0; q < 8; ++q) {
            int idx = q * 512 + t;
            long long gr = r0 + (idx >> 6);
            if (gr >= N) gr = N - 1;
            stg[q] = ((const float4*)node_ft)[gr * 64 + (idx & 63)];
        }
#pragma unroll
        for (int q = 0; q < 8; ++q) {
            float c = stg[q].x - stg[q].y + stg[q].z - stg[q].w;
            c = waveSum(c);
            int row = q * 8 + wv;
            if ((t & 63) == 0 && r0 + row < N)
                g_NF[(r0 + row) * NFW + 256] = (_Float16)c;
        }
        stage_write(smem, stg, t);
    }
    __syncthreads();

    const int lane = t & 63;
    const int mw = wv >> 2, nw = wv & 3;
    const int l15 = lane & 15, lg = lane >> 4;

    // GEMM-F: tiles tn = nw + 4j (16 tiles, uniform)
    {
        f32x4 acc[2][4] = {};
#pragma unroll
        for (int ks = 0; ks < 8; ++ks) {
            half8 a0 = *(const half8*)((char*)A + ((2 * mw + 0) * 8 + ks) * 1024 + ((lane * 16) ^ (ks << 4)));
            half8 a1 = *(const half8*)((char*)A + ((2 * mw + 1) * 8 + ks) * 1024 + ((lane * 16) ^ (ks << 4)));
#pragma unroll
            for (int j = 0; j < 4; ++j) {
                int tn = nw + 4 * j;
                half8 bf = *(const half8*)(g_FB + ((size_t)(ks * 20 + tn) * 64 + lane) * 8);
                acc[0][j] = MFMA16F(a0, bf, acc[0][j], 0, 0, 0);
                acc[1][j] = MFMA16F(a1, bf, acc[1][j], 0, 0, 0);
            }
        }
#pragma unroll
        for (int mt = 0; mt < 2; ++mt)
#pragma unroll
            for (int j = 0; j < 4; ++j) {
                int r2 = (nw + 4 * j) * 16 + l15;
#pragma unroll
                for (int r = 0; r < 4; ++r) {
                    long long gr = r0 + (2 * mw + mt) * 16 + lg * 4 + r;
                    if (gr < N) g_NF[gr * NFW + r2] = (_Float16)acc[mt][j][r];
                }
            }
    }
    // GEMM-W: write loop_msg + bias into d_out
    {
        f32x4 acc[2][4] = {};
#pragma unroll
        for (int ks = 0; ks < 8; ++ks) {
            half8 a0 = *(const half8*)((char*)A + ((2 * mw + 0) * 8 + ks) * 1024 + ((lane * 16) ^ (ks << 4)));
            half8 a1 = *(const half8*)((char*)A + ((2 * mw + 1) * 8 + ks) * 1024 + ((lane * 16) ^ (ks << 4)));
#pragma unroll
            for (int j = 0; j < 4; ++j) {
                half8 bf = *(const half8*)(g_WLEB + ((size_t)(ks * 16 + 4 * nw + j) * 64 + lane) * 8);
                acc[0][j] = MFMA16F(a0, bf, acc[0][j], 0, 0, 0);
                acc[1][j] = MFMA16F(a1, bf, acc[1][j], 0, 0, 0);
            }
        }
#pragma unroll
        for (int j = 0; j < 4; ++j) {
            const int col = (4 * nw + j) * 16 + l15;
            const float bj = w_bias[col];
#pragma unroll
            for (int mt = 0; mt < 2; ++mt)
#pragma unroll
                for (int r = 0; r < 4; ++r) {
                    long long gr = r0 + (2 * mw + mt) * 16 + lg * 4 + r;
                    if (gr < N)
                        out[gr * 256 + col] = acc[mt][j][r] + bj;
                }
        }
    }
}

// ---------------------------------------------------------------------------
// edge kernel: 64 dst-sorted edges/block, XCD-chunked tile assignment, and
// __launch_bounds__(512,8) -> VGPR<=64 -> 4 independent blocks/CU (LDS
// 4 x 33.8KB = 135KB). More independent phase chains per CU to overlap the
// serial stage->GEMM1->Hadamard->GEMM2->scatter latency.
// ---------------------------------------------------------------------------
__global__ __launch_bounds__(512, 8) void edge_kernel(
    const float* __restrict__ edge_ft, const float* __restrict__ norm,
    const int* __restrict__ src, const int* __restrict__ dst,
    float* __restrict__ agg, int E) {
    __shared__ char smem[32768 + 1024];
    unsigned short* A = (unsigned short*)smem;
    unsigned short* Z = (unsigned short*)smem;       // alias (barrier-guarded)
    int*   sdd  = (int*)(smem + 32768);              // 64 dsts
    float* snrm = (float*)(smem + 32768 + 256);      // 64 norms
    int*   ssrc = (int*)(smem + 32768 + 512);        // 64 srcs
    float* nyq  = (float*)(smem + 32768 + 768);      // EF nyquist -> Z nyquist

    // bijective XCD-chunked remap (m204)
    const int nwg = gridDim.x;
    const int q = nwg >> 3, r = nwg & 7;
    const int xcd = blockIdx.x & 7, bidx = blockIdx.x >> 3;
    const int tile = (xcd < r ? xcd * (q + 1) : r * (q + 1) + (xcd - r) * q) + bidx;

    const int t = threadIdx.x;
    const long long ebase = (long long)tile * 64;
    const int lane = t & 63, wv = t >> 6;
    const int mw = wv >> 2, nw = wv & 3;
    const int l15 = lane & 15, lg = lane >> 4;
    const bool odd = (l15 & 1);

    if (t < 64) {
        long long ge = ebase + t;
        if (ge >= E) ge = E - 1;
        int p = g_perm[ge];
        int d = dst[p];
        sdd[t] = d;
        snrm[t] = norm[d];
        ssrc[t] = src[p];
    }

    // stage edge rows (perm gather; each row 1KB coalesced) + Nyquist alt-sum
    {
        float4 stg[8];
#pragma unroll
        for (int q2 = 0; q2 < 8; ++q2) {
            long long ge = ebase + q2 * 8 + wv;
            if (ge >= E) ge = E - 1;
            stg[q2] = ((const float4*)edge_ft)[(long long)g_perm[ge] * 64 + lane];
        }
#pragma unroll
        for (int q2 = 0; q2 < 8; ++q2) {
            float c = stg[q2].x - stg[q2].y + stg[q2].z - stg[q2].w;
            c = waveSum(c);
            if (lane == 0) nyq[q2 * 8 + wv] = c;
        }
        stage_write(smem, stg, t);
    }
    __syncthreads();

    // GEMM1: EF tiles tn = nw + 4j (16 tiles, uniform)
    f32x4 acc1[2][4] = {};
#pragma unroll
    for (int ks = 0; ks < 8; ++ks) {
        half8 a0 = *(const half8*)((char*)A + ((2 * mw + 0) * 8 + ks) * 1024 + ((lane * 16) ^ (ks << 4)));
        half8 a1 = *(const half8*)((char*)A + ((2 * mw + 1) * 8 + ks) * 1024 + ((lane * 16) ^ (ks << 4)));
#pragma unroll
        for (int j = 0; j < 4; ++j) {
            int tn = nw + 4 * j;
            half8 bf = *(const half8*)(g_FB + ((size_t)(ks * 20 + tn) * 64 + lane) * 8);
            acc1[0][j] = MFMA16F(a0, bf, acc1[0][j], 0, 0, 0);
            acc1[1][j] = MFMA16F(a1, bf, acc1[1][j], 0, 0, 0);
        }
    }
    __syncthreads();  // A reads done; Z may overwrite

    // Z nyquist: Znyq[e] = EFnyq[e] * NFnyq[src[e]]
    if (t < 64)
        nyq[t] = nyq[t] * (float)g_NF[(size_t)ssrc[t] * NFW + 256];

    // Hadamard: Z = conj(NF[src]) * EF, fp16 into A-frag layout (8 chunks)
#pragma unroll
    for (int mt = 0; mt < 2; ++mt) {
        int tm = 2 * mw + mt;
#pragma unroll
        for (int r2i = 0; r2i < 4; ++r2i) {
            int e = tm * 16 + lg * 4 + r2i;
            const char* nfrow = (const char*)(g_NF + (size_t)ssrc[e] * NFW);
#pragma unroll
            for (int j = 0; j < 4; ++j) {
                int r2 = (nw + 4 * j) * 16 + l15;
                float own = acc1[mt][j][r2i];
                float oth = __shfl_xor(own, 1);
                union { unsigned int u; half2v h; } cv;
                cv.u = *(const unsigned int*)(nfrow + (r2 & ~1) * 2);
                float br = (float)cv.h[0], bi = (float)cv.h[1];
                float z = odd ? (br * own - bi * oth) : (br * own + bi * oth);
                int ksz = r2 >> 5;
                int off = (tm * 8 + ksz) * 1024 +
                          ((((((r2 >> 3) & 3) << 4) | (e & 15)) * 16) ^ (ksz << 4)) +
                          (r2 & 7) * 2;
                *(unsigned short*)((char*)Z + off) = f2hu(z);
            }
        }
    }
    __syncthreads();

    // GEMM2: msg = Z @ Chat (K = 256) + Nyquist rank-1
    f32x4 acc2[2][4] = {};
#pragma unroll
    for (int ks = 0; ks < 8; ++ks) {
        half8 a0 = *(const half8*)((char*)Z + ((2 * mw + 0) * 8 + ks) * 1024 + ((lane * 16) ^ (ks << 4)));
        half8 a1 = *(const half8*)((char*)Z + ((2 * mw + 1) * 8 + ks) * 1024 + ((lane * 16) ^ (ks << 4)));
#pragma unroll
        for (int j = 0; j < 4; ++j) {
            half8 bf = *(const half8*)(g_CB + ((size_t)(ks * 16 + 4 * nw + j) * 64 + lane) * 8);
            acc2[0][j] = MFMA16F(a0, bf, acc2[0][j], 0, 0, 0);
            acc2[1][j] = MFMA16F(a1, bf, acc2[1][j], 0, 0, 0);
        }
    }
    {
        float c256[4];
#pragma unroll
        for (int j = 0; j < 4; ++j) c256[j] = g_C256[(4 * nw + j) * 16 + l15];
#pragma unroll
        for (int mt = 0; mt < 2; ++mt)
#pragma unroll
            for (int r2i = 0; r2i < 4; ++r2i) {
                float zn = nyq[(2 * mw + mt) * 16 + lg * 4 + r2i];
#pragma unroll
                for (int j = 0; j < 4; ++j)
                    acc2[mt][j][r2i] = fmaf(zn, c256[j], acc2[mt][j][r2i]);
            }
    }

    // scatter: norm-scaled, dst-run compressed (sorted order)
#pragma unroll
    for (int mt = 0; mt < 2; ++mt) {
        const int e0 = (2 * mw + mt) * 16 + lg * 4;
        const bool v0 = ebase + e0 < E, v1 = ebase + e0 + 1 < E;
        const bool v2 = ebase + e0 + 2 < E, v3 = ebase + e0 + 3 < E;
        const int d0 = sdd[e0], d1 = sdd[e0 + 1], d2 = sdd[e0 + 2], d3 = sdd[e0 + 3];
        const float n0 = snrm[e0], n1 = snrm[e0 + 1], n2 = snrm[e0 + 2], n3 = snrm[e0 + 3];
        const bool uni = v3 && (d0 == d1) && (d1 == d2) && (d2 == d3);
        const bool p01 = v1 && (d0 == d1);
        const bool p23 = v3 && (d2 == d3);
#pragma unroll
        for (int j = 0; j < 4; ++j) {
            const int col = (4 * nw + j) * 16 + l15;
            float x0 = acc2[mt][j][0] * n0, x1 = acc2[mt][j][1] * n1;
            float x2 = acc2[mt][j][2] * n2, x3 = acc2[mt][j][3] * n3;
            if (uni) {
                atomAddF(agg + (long long)d0 * 256 + col, (x0 + x1) + (x2 + x3));
            } else {
                if (p01) atomAddF(agg + (long long)d0 * 256 + col, x0 + x1);
                else {
                    if (v0) atomAddF(agg + (long long)d0 * 256 + col, x0);
                    if (v1) atomAddF(agg + (long long)d1 * 256 + col, x1);
                }
                if (p23) atomAddF(agg + (long long)d2 * 256 + col, x2 + x3);
                else {
                    if (v2) atomAddF(agg + (long long)d2 * 256 + col, x2);
                    if (v3) atomAddF(agg + (long long)d3 * 256 + col, x3);
                }
            }
        }
    }
}

// ---------------------------------------------------------------------------
// stats: per-column sum / sumsq of h (= d_out) for BN
// ---------------------------------------------------------------------------
__global__ __launch_bounds__(256) void stats_kernel(
    const float* __restrict__ h, float* __restrict__ s1g,
    float* __restrict__ s2g, long long tot4) {
    __shared__ float s1l[256], s2l[256];
    const int t = threadIdx.x;
    s1l[t] = 0.f;
    s2l[t] = 0.f;
    __syncthreads();
    const int dg = t & 63;
    float a1[4] = {0.f, 0.f, 0.f, 0.f}, a2[4] = {0.f, 0.f, 0.f, 0.f};
    const long long stride = (long long)gridDim.x * 256;
    for (long long i4 = (long long)blockIdx.x * 256 + t; i4 < tot4; i4 += stride) {
        float4 v = ((const float4*)h)[i4];
        a1[0] += v.x; a2[0] += v.x * v.x;
        a1[1] += v.y; a2[1] += v.y * v.y;
        a1[2] += v.z; a2[2] += v.z * v.z;
        a1[3] += v.w; a2[3] += v.w * v.w;
    }
#pragma unroll
    for (int c = 0; c < 4; ++c) {
        atomicAdd(&s1l[dg * 4 + c], a1[c]);
        atomicAdd(&s2l[dg * 4 + c], a2[c]);
    }
    __syncthreads();
    atomAddF(&s1g[t], s1l[t]);
    atomAddF(&s2g[t], s2l[t]);
}

// ---------------------------------------------------------------------------
// finalize: out = tanh((h - mean) * rsqrt(var + eps) * gamma + beta)
// ---------------------------------------------------------------------------
__global__ __launch_bounds__(256) void finalize_kernel(
    float* __restrict__ out, const float* __restrict__ s1g,
    const float* __restrict__ s2g, const float* __restrict__ gamma,
    const float* __restrict__ beta, int N) {
    long long i4 = (long long)blockIdx.x * blockDim.x + threadIdx.x;
    long long tot = (long long)N * 64;
    if (i4 >= tot) return;
    const int dg = (int)(i4 & 63);
    float4 h = ((float4*)out)[i4];
    const float4 s1 = ((const float4*)s1g)[dg];
    const float4 s2 = ((const float4*)s2g)[dg];
    const float4 g = ((const float4*)gamma)[dg];
    const float4 b = ((const float4*)beta)[dg];
    const float invN = 1.f / (float)N;
    float4 o;
    { float m = s1.x * invN; float v = s2.x * invN - m * m;
      o.x = tanhf(fmaf(h.x - m, rsqrtf(v + BN_EPS) * g.x, b.x)); }
    { float m = s1.y * invN; float v = s2.y * invN - m * m;
      o.y = tanhf(fmaf(h.y - m, rsqrtf(v + BN_EPS) * g.y, b.y)); }
    { float m = s1.z * invN; float v = s2.z * invN - m * m;
      o.z = tanhf(fmaf(h.z - m, rsqrtf(v + BN_EPS) * g.z, b.z)); }
    { float m = s1.w * invN; float v = s2.w * invN - m * m;
      o.w = tanhf(fmaf(h.w - m, rsqrtf(v + BN_EPS) * g.w, b.w)); }
    ((float4*)out)[i4] = o;
}

// ---------------------------------------------------------------------------
extern "C" void kernel_launch(void* const* d_in, const int* in_sizes, int n_in,
                              void* d_out, int out_size, void* d_ws, size_t ws_size,
                              hipStream_t stream) {
    const float* node_ft  = (const float*)d_in[0];
    const float* edge_ft  = (const float*)d_in[1];
    const float* norm     = (const float*)d_in[2];
    const float* w_loop   = (const float*)d_in[3];
    const float* w_in     = (const float*)d_in[4];
    const float* loop_rel = (const float*)d_in[5];
    const float* w_bias   = (const float*)d_in[6];
    const float* bn_gamma = (const float*)d_in[7];
    const float* bn_beta  = (const float*)d_in[8];
    const int*   src      = (const int*)d_in[9];
    const int*   dst      = (const int*)d_in[10];

    const int N = in_sizes[2];
    const int E = in_sizes[9];
    float* out = (float*)d_out;

    float* s1g = (float*)d_ws;
    float* s2g = s1g + 256;

    hipMemsetAsync(d_ws, 0, 512 * sizeof(float), stream);

    float* Wle_ptr = nullptr;
    hipGetSymbolAddress((void**)&Wle_ptr, HIP_SYMBOL(g_Wle));
    void* hist_ptr = nullptr;
    hipGetSymbolAddress(&hist_ptr, HIP_SYMBOL(g_hist));
    hipMemsetAsync(hist_ptr, 0, (size_t)N * sizeof(int), stream);

    const int sblk = (N + 511) / 512;
    const int eblk = (E + 511) / 512;

    // dst counting sort -> g_perm
    hist_kernel<<<eblk, 512, 0, stream>>>(dst, E);
    scanA_kernel<<<sblk, 512, 0, stream>>>(N);
    scanB_kernel<<<1, 128, 0, stream>>>(sblk);
    scanC_kernel<<<sblk, 512, 0, stream>>>(N);
    perm_kernel<<<eblk, 512, 0, stream>>>(dst, E);

    // constant packs
    wle_kernel<<<256, 256, 0, stream>>>(loop_rel, w_loop, Wle_ptr);
    fb_pack<<<8 * 20, 512, 0, stream>>>();
    cb_pack<<<9 * 16, 512, 0, stream>>>(w_in);
    wleb_pack<<<8 * 16, 512, 0, stream>>>();

    // node pass -> NF + (loop_msg + bias) in d_out
    nfloop_kernel<<<(N + 63) / 64, 512, 0, stream>>>(node_ft, w_bias, out, N);
    // fused edge pass, XCD-chunked, 4 blocks/CU
    edge_kernel<<<(E + 63) / 64, 512, 0, stream>>>(edge_ft, norm, src, dst, out, E);
    stats_kernel<<<1024, 256, 0, stream>>>(out, s1g, s2g, (long long)N * 64);
    finalize_kernel<<<(int)(((long long)N * 64 + 255) / 256), 256, 0, stream>>>(
        out, s1g, s2g, bn_gamma, bn_beta, N);
}

// Round 14
// 452.008 us; speedup vs baseline: 1.2089x; 1.2089x over previous
//
#include <hip/hip_runtime.h>
#include <hip/hip_bf16.h>

#define NN 50000
#define EE 300000
#define BN_EPS 1e-5f
#define NFW 288            // NF row stride in fp16 elems
#define TWOPI_256 0.024543692606170259f  // 2*pi/256

typedef __attribute__((ext_vector_type(8))) _Float16 half8;
typedef __attribute__((ext_vector_type(2))) _Float16 half2v;
typedef __attribute__((ext_vector_type(4))) float f32x4;
#define MFMA16F __builtin_amdgcn_mfma_f32_16x16x32_f16

// ---- static device scratch ----
__device__ __align__(16) _Float16 g_NF[(size_t)NN * NFW];  // node rfft table, fp16
__device__ float g_Wle[256 * 256];                         // folded loop matrix, fp32
__device__ float g_C256[256];                              // Chat row 256 (Nyquist), fp32
// B operands pre-swizzled into MFMA fragment order: [ks][ntile][lane][8]
__device__ __align__(16) unsigned short g_FB[8 * 20 * 64 * 8];   // rfft matrix F
__device__ __align__(16) unsigned short g_CB[9 * 16 * 64 * 8];   // Chat
__device__ __align__(16) unsigned short g_WLEB[8 * 16 * 64 * 8]; // W_le
// dst counting-sort scratch
__device__ int g_hist[NN];
__device__ int g_off[NN + 1];
__device__ int g_cursor[NN];
__device__ int g_perm[EE];
__device__ int g_bsum[128];
__device__ int g_bbase[128];

__device__ __forceinline__ void atomAddF(float* p, float v) { unsafeAtomicAdd(p, v); }

__device__ __forceinline__ unsigned short f2hu(float x) {
    union { _Float16 f; unsigned short u; } c;
    c.f = (_Float16)x;
    return c.u;
}

// ---------------------------------------------------------------------------
// staged fp32 regs -> fp16 MFMA A-fragments in LDS (XOR-swizzled), 8 chunks.
// lane l of tile m, kstep ks holds A[m*16+(l&15)][32*ks+8*(l>>4)+e].
// ---------------------------------------------------------------------------
__device__ __forceinline__ void stage_write(char* A, const float4* stg, int t) {
#pragma unroll
    for (int q = 0; q < 8; ++q) {
        int idx = q * 512 + t;
        int row = idx >> 6, c4 = idx & 63;
        union { _Float16 f[4]; ushort4 u; } r;
        r.f[0] = (_Float16)stg[q].x; r.f[1] = (_Float16)stg[q].y;
        r.f[2] = (_Float16)stg[q].z; r.f[3] = (_Float16)stg[q].w;
        int ks = c4 >> 3;
        int off = ((row >> 4) * 8 + ks) * 1024 +
                  ((((((c4 >> 1) & 3) << 4) | (row & 15)) * 16) ^ (ks << 4)) +
                  (c4 & 1) * 8;
        *(ushort4*)(A + off) = r.u;
    }
}

// full-wave sum of v across 64 lanes
__device__ __forceinline__ float waveSum(float v) {
#pragma unroll
    for (int d = 1; d < 64; d <<= 1) v += __shfl_xor(v, d);
    return v;
}

// ---------------------------------------------------------------------------
// dst counting sort: hist -> 2-level exclusive scan -> permutation
// ---------------------------------------------------------------------------
__global__ __launch_bounds__(512) void hist_kernel(const int* __restrict__ dst, int E) {
    int e = blockIdx.x * 512 + threadIdx.x;
    if (e < E) atomicAdd(&g_hist[dst[e]], 1);
}

__global__ __launch_bounds__(512) void scanA_kernel(int N) {
    __shared__ int arr[512];
    int t = threadIdx.x, b = blockIdx.x * 512 + t;
    int cnt = (b < N) ? g_hist[b] : 0;
    arr[t] = cnt;
    __syncthreads();
#pragma unroll
    for (int off = 1; off < 512; off <<= 1) {
        int v = (t >= off) ? arr[t - off] : 0;
        __syncthreads();
        arr[t] += v;
        __syncthreads();
    }
    if (b < N) g_off[b] = arr[t] - cnt;
    if (t == 511) g_bsum[blockIdx.x] = arr[511];
}

__global__ __launch_bounds__(128) void scanB_kernel(int nblk) {
    __shared__ int arr[128];
    int t = threadIdx.x;
    int v0 = (t < nblk) ? g_bsum[t] : 0;
    arr[t] = v0;
    __syncthreads();
#pragma unroll
    for (int off = 1; off < 128; off <<= 1) {
        int v = (t >= off) ? arr[t - off] : 0;
        __syncthreads();
        arr[t] += v;
        __syncthreads();
    }
    if (t < nblk) g_bbase[t] = arr[t] - v0;
}

__global__ __launch_bounds__(512) void scanC_kernel(int N) {
    int b = blockIdx.x * 512 + threadIdx.x;
    if (b < N) {
        int v = g_off[b] + g_bbase[blockIdx.x];
        g_off[b] = v;
        g_cursor[b] = v;
        if (b == N - 1) g_off[N] = v + g_hist[b];
    }
}

__global__ __launch_bounds__(512) void perm_kernel(const int* __restrict__ dst, int E) {
    int e = blockIdx.x * 512 + threadIdx.x;
    if (e < E) {
        int pos = atomicAdd(&g_cursor[dst[e]], 1);
        g_perm[pos] = e;
    }
}

// ---------------------------------------------------------------------------
// K1: W_le[j][d] = sum_k loop_rel[(j+k)%256] * w_loop[k][d]
// ---------------------------------------------------------------------------
__global__ __launch_bounds__(256) void wle_kernel(
    const float* __restrict__ loop_rel, const float* __restrict__ w_loop,
    float* __restrict__ W_le) {
    __shared__ float lr[256];
    const int d = threadIdx.x, j = blockIdx.x;
    lr[d] = loop_rel[d];
    __syncthreads();
    float acc = 0.f;
#pragma unroll 4
    for (int k = 0; k < 256; ++k)
        acc = fmaf(lr[(j + k) & 255], w_loop[k * 256 + d], acc);
    W_le[j * 256 + d] = acc;
}

// ---------------------------------------------------------------------------
// pack F into B-fragment order, fp16
// ---------------------------------------------------------------------------
__global__ __launch_bounds__(512) void fb_pack() {
    int b = blockIdx.x, ks = b / 20, nt = b % 20;
    int t = threadIdx.x, lane = t >> 3, e = t & 7;
    int k = 32 * ks + 8 * (lane >> 4) + e;
    int r2 = nt * 16 + (lane & 15);
    float val = 0.f;
    if (r2 < 258) {
        int f = r2 >> 1;
        int m = (f * k) & 255;
        float s, c;
        sincosf((float)m * TWOPI_256, &s, &c);
        val = (r2 & 1) ? -s : c;
    }
    g_FB[((ks * 20 + nt) * 64 + lane) * 8 + e] = f2hu(val);
}

// ---------------------------------------------------------------------------
// pack Chat into B-fragment order, fp16; also emit fp32 row 256 -> g_C256.
// ---------------------------------------------------------------------------
__global__ __launch_bounds__(512) void cb_pack(const float* __restrict__ w_in) {
    __shared__ float ct[256], st[256];
    int t = threadIdx.x;
    if (t < 256) {
        float s, c;
        sincosf((float)t * TWOPI_256, &s, &c);
        ct[t] = c; st[t] = s;
    }
    __syncthreads();
    int b = blockIdx.x, ks = b / 16, nt = b % 16;
    int lane = t >> 3, e = t & 7;
    int kk = 32 * ks + 8 * (lane >> 4) + e;
    int d = nt * 16 + (lane & 15);
    float val = 0.f;
    if (kk < 258) {
        int f = kk >> 1;
        float cf = (f == 0 || f == 128) ? (1.f / 256.f) : (2.f / 256.f);
        const float* tab = (kk & 1) ? st : ct;
        float sgn = (kk & 1) ? -1.f : 1.f;
        float acc = 0.f;
        for (int k = 0; k < 256; ++k)
            acc = fmaf(tab[(f * k) & 255], w_in[k * 256 + d], acc);
        val = cf * sgn * acc;
    }
    if (kk == 256) g_C256[d] = val;   // Nyquist row, fp32
    g_CB[((ks * 16 + nt) * 64 + lane) * 8 + e] = f2hu(val);
}

// pack W_le into B-fragment order, fp16.
__global__ __launch_bounds__(512) void wleb_pack() {
    int b = blockIdx.x, ks = b / 16, nt = b % 16;
    int t = threadIdx.x, lane = t >> 3, e = t & 7;
    int k = 32 * ks + 8 * (lane >> 4) + e;
    int d = nt * 16 + (lane & 15);
    g_WLEB[((ks * 16 + nt) * 64 + lane) * 8 + e] = f2hu(g_Wle[k * 256 + d]);
}

// ---------------------------------------------------------------------------
// nfloop: per 64 node rows: NF = node @ F (cols 0..255 via MFMA; col 256 =
// alternating sum via wave-reduce during staging), d_out = node @ W_le + bias.
// ---------------------------------------------------------------------------
__global__ __launch_bounds__(512, 4) void nfloop_kernel(
    const float* __restrict__ node_ft, const float* __restrict__ w_bias,
    float* __restrict__ out, int N) {
    __shared__ char smem[32768];
    unsigned short* A = (unsigned short*)smem;
    const int t = threadIdx.x;
    const int wv = t >> 6;
    const long long r0 = (long long)blockIdx.x * 64;
    {
        float4 stg[8];
#pragma unroll
        for (int q = 0; q < 8; ++q) {
            int idx = q * 512 + t;
            long long gr = r0 + (idx >> 6);
            if (gr >= N) gr = N - 1;
            stg[q] = ((const float4*)node_ft)[gr * 64 + (idx & 63)];
        }
#pragma unroll
        for (int q = 0; q < 8; ++q) {
            float c = stg[q].x - stg[q].y + stg[q].z - stg[q].w;
            c = waveSum(c);
            int row = q * 8 + wv;
            if ((t & 63) == 0 && r0 + row < N)
                g_NF[(r0 + row) * NFW + 256] = (_Float16)c;
        }
        stage_write(smem, stg, t);
    }
    __syncthreads();

    const int lane = t & 63;
    const int mw = wv >> 2, nw = wv & 3;
    const int l15 = lane & 15, lg = lane >> 4;

    // GEMM-F: tiles tn = nw + 4j (16 tiles, uniform)
    {
        f32x4 acc[2][4] = {};
#pragma unroll
        for (int ks = 0; ks < 8; ++ks) {
            half8 a0 = *(const half8*)((char*)A + ((2 * mw + 0) * 8 + ks) * 1024 + ((lane * 16) ^ (ks << 4)));
            half8 a1 = *(const half8*)((char*)A + ((2 * mw + 1) * 8 + ks) * 1024 + ((lane * 16) ^ (ks << 4)));
#pragma unroll
            for (int j = 0; j < 4; ++j) {
                int tn = nw + 4 * j;
                half8 bf = *(const half8*)(g_FB + ((size_t)(ks * 20 + tn) * 64 + lane) * 8);
                acc[0][j] = MFMA16F(a0, bf, acc[0][j], 0, 0, 0);
                acc[1][j] = MFMA16F(a1, bf, acc[1][j], 0, 0, 0);
            }
        }
#pragma unroll
        for (int mt = 0; mt < 2; ++mt)
#pragma unroll
            for (int j = 0; j < 4; ++j) {
                int r2 = (nw + 4 * j) * 16 + l15;
#pragma unroll
                for (int r = 0; r < 4; ++r) {
                    long long gr = r0 + (2 * mw + mt) * 16 + lg * 4 + r;
                    if (gr < N) g_NF[gr * NFW + r2] = (_Float16)acc[mt][j][r];
                }
            }
    }
    // GEMM-W: write loop_msg + bias into d_out
    {
        f32x4 acc[2][4] = {};
#pragma unroll
        for (int ks = 0; ks < 8; ++ks) {
            half8 a0 = *(const half8*)((char*)A + ((2 * mw + 0) * 8 + ks) * 1024 + ((lane * 16) ^ (ks << 4)));
            half8 a1 = *(const half8*)((char*)A + ((2 * mw + 1) * 8 + ks) * 1024 + ((lane * 16) ^ (ks << 4)));
#pragma unroll
            for (int j = 0; j < 4; ++j) {
                half8 bf = *(const half8*)(g_WLEB + ((size_t)(ks * 16 + 4 * nw + j) * 64 + lane) * 8);
                acc[0][j] = MFMA16F(a0, bf, acc[0][j], 0, 0, 0);
                acc[1][j] = MFMA16F(a1, bf, acc[1][j], 0, 0, 0);
            }
        }
#pragma unroll
        for (int j = 0; j < 4; ++j) {
            const int col = (4 * nw + j) * 16 + l15;
            const float bj = w_bias[col];
#pragma unroll
            for (int mt = 0; mt < 2; ++mt)
#pragma unroll
                for (int r = 0; r < 4; ++r) {
                    long long gr = r0 + (2 * mw + mt) * 16 + lg * 4 + r;
                    if (gr < N)
                        out[gr * 256 + col] = acc[mt][j][r] + bj;
                }
        }
    }
}

// ---------------------------------------------------------------------------
// edge kernel: 64 dst-sorted edges/block, XCD-chunked tile assignment.
// NF rows for the tile are BULK-STAGED into LDS once (read-once burst ->
// smaller L2 working set; Hadamard becomes pure LDS). 2 blocks/CU (71KB LDS).
// EF = y@F -> Z = conj(NF_lds)*EF -> msg = Z@Chat + Nyquist rank-1
// -> norm-scaled compressed atomic scatter into d_out.
// ---------------------------------------------------------------------------
__global__ __launch_bounds__(512, 4) void edge_kernel(
    const float* __restrict__ edge_ft, const float* __restrict__ norm,
    const int* __restrict__ src, const int* __restrict__ dst,
    float* __restrict__ agg, int E) {
    __shared__ char smem[32768 + 1024 + 64 * 584];
    unsigned short* A = (unsigned short*)smem;
    unsigned short* Z = (unsigned short*)smem;       // alias (barrier-guarded)
    int*   sdd  = (int*)(smem + 32768);              // 64 dsts
    float* snrm = (float*)(smem + 32768 + 256);      // 64 norms
    float* nyq  = (float*)(smem + 32768 + 512);      // EF nyquist -> Z nyquist
    char*  NFL  = smem + 33792;                      // 64 NF rows x 584B

    // bijective XCD-chunked remap (m204)
    const int nwg = gridDim.x;
    const int qq = nwg >> 3, rr = nwg & 7;
    const int xcd = blockIdx.x & 7, bidx = blockIdx.x >> 3;
    const int tile = (xcd < rr ? xcd * (qq + 1) : rr * (qq + 1) + (xcd - rr) * qq) + bidx;

    const int t = threadIdx.x;
    const long long ebase = (long long)tile * 64;
    const int lane = t & 63, wv = t >> 6;
    const int mw = wv >> 2, nw = wv & 3;
    const int l15 = lane & 15, lg = lane >> 4;
    const bool odd = (l15 & 1);

    if (t < 64) {
        long long ge = ebase + t;
        if (ge >= E) ge = E - 1;
        int p = g_perm[ge];
        int d = dst[p];
        sdd[t] = d;
        snrm[t] = norm[d];
    }

    // stage edge rows (perm gather; each row 1KB coalesced) + Nyquist alt-sum
    {
        float4 stg[8];
#pragma unroll
        for (int q2 = 0; q2 < 8; ++q2) {
            long long ge = ebase + q2 * 8 + wv;
            if (ge >= E) ge = E - 1;
            stg[q2] = ((const float4*)edge_ft)[(long long)g_perm[ge] * 64 + lane];
        }

        // NF rows of this tile's srcs -> LDS (64 rows x 576B, 16B coalesced,
        // read ONCE per block; 2304 chunks over 512 threads). perm/src loads
        // are 64-value L1-hot broadcasts.
#pragma unroll
        for (int q3 = 0; q3 < 5; ++q3) {
            int idx = q3 * 512 + t;
            if (idx < 2304) {
                int row = idx / 36, c16 = idx - row * 36;
                long long ge = ebase + row;
                if (ge >= E) ge = E - 1;
                int srow = src[g_perm[ge]];
                int4 v = *(const int4*)((const char*)g_NF + (size_t)srow * 576 + c16 * 16);
                *(int4*)(NFL + row * 584 + c16 * 16) = v;
            }
        }

#pragma unroll
        for (int q2 = 0; q2 < 8; ++q2) {
            float c = stg[q2].x - stg[q2].y + stg[q2].z - stg[q2].w;
            c = waveSum(c);
            if (lane == 0) nyq[q2 * 8 + wv] = c;
        }
        stage_write(smem, stg, t);
    }
    __syncthreads();

    // GEMM1: EF tiles tn = nw + 4j (16 tiles, uniform)
    f32x4 acc1[2][4] = {};
#pragma unroll
    for (int ks = 0; ks < 8; ++ks) {
        half8 a0 = *(const half8*)((char*)A + ((2 * mw + 0) * 8 + ks) * 1024 + ((lane * 16) ^ (ks << 4)));
        half8 a1 = *(const half8*)((char*)A + ((2 * mw + 1) * 8 + ks) * 1024 + ((lane * 16) ^ (ks << 4)));
#pragma unroll
        for (int j = 0; j < 4; ++j) {
            int tn = nw + 4 * j;
            half8 bf = *(const half8*)(g_FB + ((size_t)(ks * 20 + tn) * 64 + lane) * 8);
            acc1[0][j] = MFMA16F(a0, bf, acc1[0][j], 0, 0, 0);
            acc1[1][j] = MFMA16F(a1, bf, acc1[1][j], 0, 0, 0);
        }
    }
    __syncthreads();  // A reads done; Z may overwrite (NFL untouched)

    // Z nyquist: Znyq[e] = EFnyq[e] * NFnyq[src[e]]  (NF col 256 = byte 512)
    if (t < 64)
        nyq[t] = nyq[t] * (float)(*(const _Float16*)(NFL + t * 584 + 512));

    // Hadamard: Z = conj(NF_lds) * EF, fp16 into A-frag layout (8 chunks).
    // NFL stride 584B = 146 dwords -> rows offset 18 banks -> spread.
#pragma unroll
    for (int mt = 0; mt < 2; ++mt) {
        int tm = 2 * mw + mt;
#pragma unroll
        for (int r2i = 0; r2i < 4; ++r2i) {
            int e = tm * 16 + lg * 4 + r2i;
            const char* nfrow = NFL + e * 584;
#pragma unroll
            for (int j = 0; j < 4; ++j) {
                int r2 = (nw + 4 * j) * 16 + l15;
                float own = acc1[mt][j][r2i];
                float oth = __shfl_xor(own, 1);
                union { unsigned int u; half2v h; } cv;
                cv.u = *(const unsigned int*)(nfrow + (r2 & ~1) * 2);
                float br = (float)cv.h[0], bi = (float)cv.h[1];
                float z = odd ? (br * own - bi * oth) : (br * own + bi * oth);
                int ksz = r2 >> 5;
                int off = (tm * 8 + ksz) * 1024 +
                          ((((((r2 >> 3) & 3) << 4) | (e & 15)) * 16) ^ (ksz << 4)) +
                          (r2 & 7) * 2;
                *(unsigned short*)((char*)Z + off) = f2hu(z);
            }
        }
    }
    __syncthreads();

    // GEMM2: msg = Z @ Chat (K = 256) + Nyquist rank-1
    f32x4 acc2[2][4] = {};
#pragma unroll
    for (int ks = 0; ks < 8; ++ks) {
        half8 a0 = *(const half8*)((char*)Z + ((2 * mw + 0) * 8 + ks) * 1024 + ((lane * 16) ^ (ks << 4)));
        half8 a1 = *(const half8*)((char*)Z + ((2 * mw + 1) * 8 + ks) * 1024 + ((lane * 16) ^ (ks << 4)));
#pragma unroll
        for (int j = 0; j < 4; ++j) {
            half8 bf = *(const half8*)(g_CB + ((size_t)(ks * 16 + 4 * nw + j) * 64 + lane) * 8);
            acc2[0][j] = MFMA16F(a0, bf, acc2[0][j], 0, 0, 0);
            acc2[1][j] = MFMA16F(a1, bf, acc2[1][j], 0, 0, 0);
        }
    }
    {
        float c256[4];
#pragma unroll
        for (int j = 0; j < 4; ++j) c256[j] = g_C256[(4 * nw + j) * 16 + l15];
#pragma unroll
        for (int mt = 0; mt < 2; ++mt)
#pragma unroll
            for (int r2i = 0; r2i < 4; ++r2i) {
                float zn = nyq[(2 * mw + mt) * 16 + lg * 4 + r2i];
#pragma unroll
                for (int j = 0; j < 4; ++j)
                    acc2[mt][j][r2i] = fmaf(zn, c256[j], acc2[mt][j][r2i]);
            }
    }

    // scatter: norm-scaled, dst-run compressed (sorted order)
#pragma unroll
    for (int mt = 0; mt < 2; ++mt) {
        const int e0 = (2 * mw + mt) * 16 + lg * 4;
        const bool v0 = ebase + e0 < E, v1 = ebase + e0 + 1 < E;
        const bool v2 = ebase + e0 + 2 < E, v3 = ebase + e0 + 3 < E;
        const int d0 = sdd[e0], d1 = sdd[e0 + 1], d2 = sdd[e0 + 2], d3 = sdd[e0 + 3];
        const float n0 = snrm[e0], n1 = snrm[e0 + 1], n2 = snrm[e0 + 2], n3 = snrm[e0 + 3];
        const bool uni = v3 && (d0 == d1) && (d1 == d2) && (d2 == d3);
        const bool p01 = v1 && (d0 == d1);
        const bool p23 = v3 && (d2 == d3);
#pragma unroll
        for (int j = 0; j < 4; ++j) {
            const int col = (4 * nw + j) * 16 + l15;
            float x0 = acc2[mt][j][0] * n0, x1 = acc2[mt][j][1] * n1;
            float x2 = acc2[mt][j][2] * n2, x3 = acc2[mt][j][3] * n3;
            if (uni) {
                atomAddF(agg + (long long)d0 * 256 + col, (x0 + x1) + (x2 + x3));
            } else {
                if (p01) atomAddF(agg + (long long)d0 * 256 + col, x0 + x1);
                else {
                    if (v0) atomAddF(agg + (long long)d0 * 256 + col, x0);
                    if (v1) atomAddF(agg + (long long)d1 * 256 + col, x1);
                }
                if (p23) atomAddF(agg + (long long)d2 * 256 + col, x2 + x3);
                else {
                    if (v2) atomAddF(agg + (long long)d2 * 256 + col, x2);
                    if (v3) atomAddF(agg + (long long)d3 * 256 + col, x3);
                }
            }
        }
    }
}

// ---------------------------------------------------------------------------
// stats: per-column sum / sumsq of h (= d_out) for BN
// ---------------------------------------------------------------------------
__global__ __launch_bounds__(256) void stats_kernel(
    const float* __restrict__ h, float* __restrict__ s1g,
    float* __restrict__ s2g, long long tot4) {
    __shared__ float s1l[256], s2l[256];
    const int t = threadIdx.x;
    s1l[t] = 0.f;
    s2l[t] = 0.f;
    __syncthreads();
    const int dg = t & 63;
    float a1[4] = {0.f, 0.f, 0.f, 0.f}, a2[4] = {0.f, 0.f, 0.f, 0.f};
    const long long stride = (long long)gridDim.x * 256;
    for (long long i4 = (long long)blockIdx.x * 256 + t; i4 < tot4; i4 += stride) {
        float4 v = ((const float4*)h)[i4];
        a1[0] += v.x; a2[0] += v.x * v.x;
        a1[1] += v.y; a2[1] += v.y * v.y;
        a1[2] += v.z; a2[2] += v.z * v.z;
        a1[3] += v.w; a2[3] += v.w * v.w;
    }
#pragma unroll
    for (int c = 0; c < 4; ++c) {
        atomicAdd(&s1l[dg * 4 + c], a1[c]);
        atomicAdd(&s2l[dg * 4 + c], a2[c]);
    }
    __syncthreads();
    atomAddF(&s1g[t], s1l[t]);
    atomAddF(&s2g[t], s2l[t]);
}

// ---------------------------------------------------------------------------
// finalize: out = tanh((h - mean) * rsqrt(var + eps) * gamma + beta)
// ---------------------------------------------------------------------------
__global__ __launch_bounds__(256) void finalize_kernel(
    float* __restrict__ out, const float* __restrict__ s1g,
    const float* __restrict__ s2g, const float* __restrict__ gamma,
    const float* __restrict__ beta, int N) {
    long long i4 = (long long)blockIdx.x * blockDim.x + threadIdx.x;
    long long tot = (long long)N * 64;
    if (i4 >= tot) return;
    const int dg = (int)(i4 & 63);
    float4 h = ((float4*)out)[i4];
    const float4 s1 = ((const float4*)s1g)[dg];
    const float4 s2 = ((const float4*)s2g)[dg];
    const float4 g = ((const float4*)gamma)[dg];
    const float4 b = ((const float4*)beta)[dg];
    const float invN = 1.f / (float)N;
    float4 o;
    { float m = s1.x * invN; float v = s2.x * invN - m * m;
      o.x = tanhf(fmaf(h.x - m, rsqrtf(v + BN_EPS) * g.x, b.x)); }
    { float m = s1.y * invN; float v = s2.y * invN - m * m;
      o.y = tanhf(fmaf(h.y - m, rsqrtf(v + BN_EPS) * g.y, b.y)); }
    { float m = s1.z * invN; float v = s2.z * invN - m * m;
      o.z = tanhf(fmaf(h.z - m, rsqrtf(v + BN_EPS) * g.z, b.z)); }
    { float m = s1.w * invN; float v = s2.w * invN - m * m;
      o.w = tanhf(fmaf(h.w - m, rsqrtf(v + BN_EPS) * g.w, b.w)); }
    ((float4*)out)[i4] = o;
}

// ---------------------------------------------------------------------------
extern "C" void kernel_launch(void* const* d_in, const int* in_sizes, int n_in,
                              void* d_out, int out_size, void* d_ws, size_t ws_size,
                              hipStream_t stream) {
    const float* node_ft  = (const float*)d_in[0];
    const float* edge_ft  = (const float*)d_in[1];
    const float* norm     = (const float*)d_in[2];
    const float* w_loop   = (const float*)d_in[3];
    const float* w_in     = (const float*)d_in[4];
    const float* loop_rel = (const float*)d_in[5];
    const float* w_bias   = (const float*)d_in[6];
    const float* bn_gamma = (const float*)d_in[7];
    const float* bn_beta  = (const float*)d_in[8];
    const int*   src      = (const int*)d_in[9];
    const int*   dst      = (const int*)d_in[10];

    const int N = in_sizes[2];
    const int E = in_sizes[9];
    float* out = (float*)d_out;

    float* s1g = (float*)d_ws;
    float* s2g = s1g + 256;

    hipMemsetAsync(d_ws, 0, 512 * sizeof(float), stream);

    float* Wle_ptr = nullptr;
    hipGetSymbolAddress((void**)&Wle_ptr, HIP_SYMBOL(g_Wle));
    void* hist_ptr = nullptr;
    hipGetSymbolAddress(&hist_ptr, HIP_SYMBOL(g_hist));
    hipMemsetAsync(hist_ptr, 0, (size_t)N * sizeof(int), stream);

    const int sblk = (N + 511) / 512;
    const int eblk = (E + 511) / 512;

    // dst counting sort -> g_perm
    hist_kernel<<<eblk, 512, 0, stream>>>(dst, E);
    scanA_kernel<<<sblk, 512, 0, stream>>>(N);
    scanB_kernel<<<1, 128, 0, stream>>>(sblk);
    scanC_kernel<<<sblk, 512, 0, stream>>>(N);
    perm_kernel<<<eblk, 512, 0, stream>>>(dst, E);

    // constant packs
    wle_kernel<<<256, 256, 0, stream>>>(loop_rel, w_loop, Wle_ptr);
    fb_pack<<<8 * 20, 512, 0, stream>>>();
    cb_pack<<<9 * 16, 512, 0, stream>>>(w_in);
    wleb_pack<<<8 * 16, 512, 0, stream>>>();

    // node pass -> NF + (loop_msg + bias) in d_out
    nfloop_kernel<<<(N + 63) / 64, 512, 0, stream>>>(node_ft, w_bias, out, N);
    // fused edge pass, XCD-chunked, NF via LDS, 2 blocks/CU
    edge_kernel<<<(E + 63) / 64, 512, 0, stream>>>(edge_ft, norm, src, dst, out, E);
    stats_kernel<<<1024, 256, 0, stream>>>(out, s1g, s2g, (long long)N * 64);
    finalize_kernel<<<(int)(((long long)N * 64 + 255) / 256), 256, 0, stream>>>(
        out, s1g, s2g, bn_gamma, bn_beta, N);
}

// Round 15
// 428.851 us; speedup vs baseline: 1.2742x; 1.0540x over previous
//
#include <hip/hip_runtime.h>
#include <hip/hip_bf16.h>

#define NN 50000
#define EE 300000
#define BN_EPS 1e-5f
#define NFW 288            // NF row stride in fp16 elems
#define TWOPI_256 0.024543692606170259f  // 2*pi/256

typedef __attribute__((ext_vector_type(8))) _Float16 half8;
typedef __attribute__((ext_vector_type(2))) _Float16 half2v;
typedef __attribute__((ext_vector_type(4))) float f32x4;
#define MFMA16F __builtin_amdgcn_mfma_f32_16x16x32_f16

// ---- static device scratch ----
__device__ __align__(16) _Float16 g_NF[(size_t)NN * NFW];  // node rfft table, fp16
__device__ float g_Wle[256 * 256];                         // folded loop matrix, fp32
__device__ float g_C256[256];                              // Chat row 256 (Nyquist), fp32
// B operands pre-swizzled into MFMA fragment order: [ks][ntile][lane][8]
__device__ __align__(16) unsigned short g_FB[8 * 20 * 64 * 8];   // rfft matrix F
__device__ __align__(16) unsigned short g_CB[9 * 16 * 64 * 8];   // Chat
__device__ __align__(16) unsigned short g_WLEB[8 * 16 * 64 * 8]; // W_le
// dst counting-sort scratch
__device__ int g_hist[NN];
__device__ int g_off[NN + 1];
__device__ int g_cursor[NN];
__device__ int g_perm[EE];
__device__ int g_bsum[128];
__device__ int g_bbase[128];

__device__ __forceinline__ void atomAddF(float* p, float v) { unsafeAtomicAdd(p, v); }

__device__ __forceinline__ unsigned short f2hu(float x) {
    union { _Float16 f; unsigned short u; } c;
    c.f = (_Float16)x;
    return c.u;
}

// ---------------------------------------------------------------------------
// staged fp32 regs -> fp16 MFMA A-fragments in LDS (XOR-swizzled), 8 chunks.
// lane l of tile m, kstep ks holds A[m*16+(l&15)][32*ks+8*(l>>4)+e].
// ---------------------------------------------------------------------------
__device__ __forceinline__ void stage_write(char* A, const float4* stg, int t) {
#pragma unroll
    for (int q = 0; q < 8; ++q) {
        int idx = q * 512 + t;
        int row = idx >> 6, c4 = idx & 63;
        union { _Float16 f[4]; ushort4 u; } r;
        r.f[0] = (_Float16)stg[q].x; r.f[1] = (_Float16)stg[q].y;
        r.f[2] = (_Float16)stg[q].z; r.f[3] = (_Float16)stg[q].w;
        int ks = c4 >> 3;
        int off = ((row >> 4) * 8 + ks) * 1024 +
                  ((((((c4 >> 1) & 3) << 4) | (row & 15)) * 16) ^ (ks << 4)) +
                  (c4 & 1) * 8;
        *(ushort4*)(A + off) = r.u;
    }
}

// full-wave sum of v across 64 lanes
__device__ __forceinline__ float waveSum(float v) {
#pragma unroll
    for (int d = 1; d < 64; d <<= 1) v += __shfl_xor(v, d);
    return v;
}

// ---------------------------------------------------------------------------
// dst counting sort: hist -> 2-level exclusive scan -> permutation
// ---------------------------------------------------------------------------
__global__ __launch_bounds__(512) void hist_kernel(const int* __restrict__ dst, int E) {
    int e = blockIdx.x * 512 + threadIdx.x;
    if (e < E) atomicAdd(&g_hist[dst[e]], 1);
}

__global__ __launch_bounds__(512) void scanA_kernel(int N) {
    __shared__ int arr[512];
    int t = threadIdx.x, b = blockIdx.x * 512 + t;
    int cnt = (b < N) ? g_hist[b] : 0;
    arr[t] = cnt;
    __syncthreads();
#pragma unroll
    for (int off = 1; off < 512; off <<= 1) {
        int v = (t >= off) ? arr[t - off] : 0;
        __syncthreads();
        arr[t] += v;
        __syncthreads();
    }
    if (b < N) g_off[b] = arr[t] - cnt;
    if (t == 511) g_bsum[blockIdx.x] = arr[511];
}

__global__ __launch_bounds__(128) void scanB_kernel(int nblk) {
    __shared__ int arr[128];
    int t = threadIdx.x;
    int v0 = (t < nblk) ? g_bsum[t] : 0;
    arr[t] = v0;
    __syncthreads();
#pragma unroll
    for (int off = 1; off < 128; off <<= 1) {
        int v = (t >= off) ? arr[t - off] : 0;
        __syncthreads();
        arr[t] += v;
        __syncthreads();
    }
    if (t < nblk) g_bbase[t] = arr[t] - v0;
}

__global__ __launch_bounds__(512) void scanC_kernel(int N) {
    int b = blockIdx.x * 512 + threadIdx.x;
    if (b < N) {
        int v = g_off[b] + g_bbase[blockIdx.x];
        g_off[b] = v;
        g_cursor[b] = v;
        if (b == N - 1) g_off[N] = v + g_hist[b];
    }
}

__global__ __launch_bounds__(512) void perm_kernel(const int* __restrict__ dst, int E) {
    int e = blockIdx.x * 512 + threadIdx.x;
    if (e < E) {
        int pos = atomicAdd(&g_cursor[dst[e]], 1);
        g_perm[pos] = e;
    }
}

// ---------------------------------------------------------------------------
// K1: W_le[j][d] = sum_k loop_rel[(j+k)%256] * w_loop[k][d]
// ---------------------------------------------------------------------------
__global__ __launch_bounds__(256) void wle_kernel(
    const float* __restrict__ loop_rel, const float* __restrict__ w_loop,
    float* __restrict__ W_le) {
    __shared__ float lr[256];
    const int d = threadIdx.x, j = blockIdx.x;
    lr[d] = loop_rel[d];
    __syncthreads();
    float acc = 0.f;
#pragma unroll 4
    for (int k = 0; k < 256; ++k)
        acc = fmaf(lr[(j + k) & 255], w_loop[k * 256 + d], acc);
    W_le[j * 256 + d] = acc;
}

// ---------------------------------------------------------------------------
// pack F into B-fragment order, fp16
// ---------------------------------------------------------------------------
__global__ __launch_bounds__(512) void fb_pack() {
    int b = blockIdx.x, ks = b / 20, nt = b % 20;
    int t = threadIdx.x, lane = t >> 3, e = t & 7;
    int k = 32 * ks + 8 * (lane >> 4) + e;
    int r2 = nt * 16 + (lane & 15);
    float val = 0.f;
    if (r2 < 258) {
        int f = r2 >> 1;
        int m = (f * k) & 255;
        float s, c;
        sincosf((float)m * TWOPI_256, &s, &c);
        val = (r2 & 1) ? -s : c;
    }
    g_FB[((ks * 20 + nt) * 64 + lane) * 8 + e] = f2hu(val);
}

// ---------------------------------------------------------------------------
// pack Chat into B-fragment order, fp16; also emit fp32 row 256 -> g_C256.
// ---------------------------------------------------------------------------
__global__ __launch_bounds__(512) void cb_pack(const float* __restrict__ w_in) {
    __shared__ float ct[256], st[256];
    int t = threadIdx.x;
    if (t < 256) {
        float s, c;
        sincosf((float)t * TWOPI_256, &s, &c);
        ct[t] = c; st[t] = s;
    }
    __syncthreads();
    int b = blockIdx.x, ks = b / 16, nt = b % 16;
    int lane = t >> 3, e = t & 7;
    int kk = 32 * ks + 8 * (lane >> 4) + e;
    int d = nt * 16 + (lane & 15);
    float val = 0.f;
    if (kk < 258) {
        int f = kk >> 1;
        float cf = (f == 0 || f == 128) ? (1.f / 256.f) : (2.f / 256.f);
        const float* tab = (kk & 1) ? st : ct;
        float sgn = (kk & 1) ? -1.f : 1.f;
        float acc = 0.f;
        for (int k = 0; k < 256; ++k)
            acc = fmaf(tab[(f * k) & 255], w_in[k * 256 + d], acc);
        val = cf * sgn * acc;
    }
    if (kk == 256) g_C256[d] = val;   // Nyquist row, fp32
    g_CB[((ks * 16 + nt) * 64 + lane) * 8 + e] = f2hu(val);
}

// pack W_le into B-fragment order, fp16.
__global__ __launch_bounds__(512) void wleb_pack() {
    int b = blockIdx.x, ks = b / 16, nt = b % 16;
    int t = threadIdx.x, lane = t >> 3, e = t & 7;
    int k = 32 * ks + 8 * (lane >> 4) + e;
    int d = nt * 16 + (lane & 15);
    g_WLEB[((ks * 16 + nt) * 64 + lane) * 8 + e] = f2hu(g_Wle[k * 256 + d]);
}

// ---------------------------------------------------------------------------
// nfloop: per 64 node rows: NF = node @ F (cols 0..255 via MFMA; col 256 =
// alternating sum via wave-reduce during staging), d_out = node @ W_le + bias.
// ---------------------------------------------------------------------------
__global__ __launch_bounds__(512, 4) void nfloop_kernel(
    const float* __restrict__ node_ft, const float* __restrict__ w_bias,
    float* __restrict__ out, int N) {
    __shared__ char smem[32768];
    unsigned short* A = (unsigned short*)smem;
    const int t = threadIdx.x;
    const int wv = t >> 6;
    const long long r0 = (long long)blockIdx.x * 64;
    {
        float4 stg[8];
#pragma unroll
        for (int q = 0; q < 8; ++q) {
            int idx = q * 512 + t;
            long long gr = r0 + (idx >> 6);
            if (gr >= N) gr = N - 1;
            stg[q] = ((const float4*)node_ft)[gr * 64 + (idx & 63)];
        }
#pragma unroll
        for (int q = 0; q < 8; ++q) {
            float c = stg[q].x - stg[q].y + stg[q].z - stg[q].w;
            c = waveSum(c);
            int row = q * 8 + wv;
            if ((t & 63) == 0 && r0 + row < N)
                g_NF[(r0 + row) * NFW + 256] = (_Float16)c;
        }
        stage_write(smem, stg, t);
    }
    __syncthreads();

    const int lane = t & 63;
    const int mw = wv >> 2, nw = wv & 3;
    const int l15 = lane & 15, lg = lane >> 4;

    // GEMM-F: tiles tn = nw + 4j (16 tiles, uniform)
    {
        f32x4 acc[2][4] = {};
#pragma unroll
        for (int ks = 0; ks < 8; ++ks) {
            half8 a0 = *(const half8*)((char*)A + ((2 * mw + 0) * 8 + ks) * 1024 + ((lane * 16) ^ (ks << 4)));
            half8 a1 = *(const half8*)((char*)A + ((2 * mw + 1) * 8 + ks) * 1024 + ((lane * 16) ^ (ks << 4)));
#pragma unroll
            for (int j = 0; j < 4; ++j) {
                int tn = nw + 4 * j;
                half8 bf = *(const half8*)(g_FB + ((size_t)(ks * 20 + tn) * 64 + lane) * 8);
                acc[0][j] = MFMA16F(a0, bf, acc[0][j], 0, 0, 0);
                acc[1][j] = MFMA16F(a1, bf, acc[1][j], 0, 0, 0);
            }
        }
#pragma unroll
        for (int mt = 0; mt < 2; ++mt)
#pragma unroll
            for (int j = 0; j < 4; ++j) {
                int r2 = (nw + 4 * j) * 16 + l15;
#pragma unroll
                for (int r = 0; r < 4; ++r) {
                    long long gr = r0 + (2 * mw + mt) * 16 + lg * 4 + r;
                    if (gr < N) g_NF[gr * NFW + r2] = (_Float16)acc[mt][j][r];
                }
            }
    }
    // GEMM-W: write loop_msg + bias into d_out
    {
        f32x4 acc[2][4] = {};
#pragma unroll
        for (int ks = 0; ks < 8; ++ks) {
            half8 a0 = *(const half8*)((char*)A + ((2 * mw + 0) * 8 + ks) * 1024 + ((lane * 16) ^ (ks << 4)));
            half8 a1 = *(const half8*)((char*)A + ((2 * mw + 1) * 8 + ks) * 1024 + ((lane * 16) ^ (ks << 4)));
#pragma unroll
            for (int j = 0; j < 4; ++j) {
                half8 bf = *(const half8*)(g_WLEB + ((size_t)(ks * 16 + 4 * nw + j) * 64 + lane) * 8);
                acc[0][j] = MFMA16F(a0, bf, acc[0][j], 0, 0, 0);
                acc[1][j] = MFMA16F(a1, bf, acc[1][j], 0, 0, 0);
            }
        }
#pragma unroll
        for (int j = 0; j < 4; ++j) {
            const int col = (4 * nw + j) * 16 + l15;
            const float bj = w_bias[col];
#pragma unroll
            for (int mt = 0; mt < 2; ++mt)
#pragma unroll
                for (int r = 0; r < 4; ++r) {
                    long long gr = r0 + (2 * mw + mt) * 16 + lg * 4 + r;
                    if (gr < N)
                        out[gr * 256 + col] = acc[mt][j][r] + bj;
                }
        }
    }
}

// ---------------------------------------------------------------------------
// edge kernel: 64 dst-sorted edges/block, XCD-chunked tile assignment so each
// XCD's L2 owns a contiguous dst range (atomic lines written back ~once).
// EF = y@F -> Z = conj(NF[src])*EF -> msg = Z@Chat + Nyquist rank-1
// -> norm-scaled compressed atomic scatter into d_out.
// 2 blocks/CU is the L2-capacity optimum (R13: 4 blocks/CU thrashed L2,
// WRITE 142->525MB; R10: same via higher occupancy without chunking).
// ---------------------------------------------------------------------------
__global__ __launch_bounds__(512, 4) void edge_kernel(
    const float* __restrict__ edge_ft, const float* __restrict__ norm,
    const int* __restrict__ src, const int* __restrict__ dst,
    float* __restrict__ agg, int E) {
    __shared__ char smem[32768 + 1024];
    unsigned short* A = (unsigned short*)smem;
    unsigned short* Z = (unsigned short*)smem;       // alias (barrier-guarded)
    int*   sdd  = (int*)(smem + 32768);              // 64 dsts
    float* snrm = (float*)(smem + 32768 + 256);      // 64 norms
    int*   ssrc = (int*)(smem + 32768 + 512);        // 64 srcs
    float* nyq  = (float*)(smem + 32768 + 768);      // EF nyquist -> Z nyquist

    // bijective XCD-chunked remap (m204)
    const int nwg = gridDim.x;
    const int q = nwg >> 3, r = nwg & 7;
    const int xcd = blockIdx.x & 7, bidx = blockIdx.x >> 3;
    const int tile = (xcd < r ? xcd * (q + 1) : r * (q + 1) + (xcd - r) * q) + bidx;

    const int t = threadIdx.x;
    const long long ebase = (long long)tile * 64;
    const int lane = t & 63, wv = t >> 6;
    const int mw = wv >> 2, nw = wv & 3;
    const int l15 = lane & 15, lg = lane >> 4;
    const bool odd = (l15 & 1);

    if (t < 64) {
        long long ge = ebase + t;
        if (ge >= E) ge = E - 1;
        int p = g_perm[ge];
        int d = dst[p];
        sdd[t] = d;
        snrm[t] = norm[d];
        ssrc[t] = src[p];
    }

    // stage edge rows (perm gather; each row 1KB coalesced) + Nyquist alt-sum
    {
        float4 stg[8];
#pragma unroll
        for (int q2 = 0; q2 < 8; ++q2) {
            long long ge = ebase + q2 * 8 + wv;
            if (ge >= E) ge = E - 1;
            stg[q2] = ((const float4*)edge_ft)[(long long)g_perm[ge] * 64 + lane];
        }
#pragma unroll
        for (int q2 = 0; q2 < 8; ++q2) {
            float c = stg[q2].x - stg[q2].y + stg[q2].z - stg[q2].w;
            c = waveSum(c);
            if (lane == 0) nyq[q2 * 8 + wv] = c;
        }
        stage_write(smem, stg, t);
    }
    __syncthreads();

    // GEMM1: EF tiles tn = nw + 4j (16 tiles, uniform)
    f32x4 acc1[2][4] = {};
#pragma unroll
    for (int ks = 0; ks < 8; ++ks) {
        half8 a0 = *(const half8*)((char*)A + ((2 * mw + 0) * 8 + ks) * 1024 + ((lane * 16) ^ (ks << 4)));
        half8 a1 = *(const half8*)((char*)A + ((2 * mw + 1) * 8 + ks) * 1024 + ((lane * 16) ^ (ks << 4)));
#pragma unroll
        for (int j = 0; j < 4; ++j) {
            int tn = nw + 4 * j;
            half8 bf = *(const half8*)(g_FB + ((size_t)(ks * 20 + tn) * 64 + lane) * 8);
            acc1[0][j] = MFMA16F(a0, bf, acc1[0][j], 0, 0, 0);
            acc1[1][j] = MFMA16F(a1, bf, acc1[1][j], 0, 0, 0);
        }
    }
    __syncthreads();  // A reads done; Z may overwrite

    // Z nyquist: Znyq[e] = EFnyq[e] * NFnyq[src[e]]
    if (t < 64)
        nyq[t] = nyq[t] * (float)g_NF[(size_t)ssrc[t] * NFW + 256];

    // Hadamard: Z = conj(NF[src]) * EF, fp16 into A-frag layout (8 chunks)
#pragma unroll
    for (int mt = 0; mt < 2; ++mt) {
        int tm = 2 * mw + mt;
#pragma unroll
        for (int r2i = 0; r2i < 4; ++r2i) {
            int e = tm * 16 + lg * 4 + r2i;
            const char* nfrow = (const char*)(g_NF + (size_t)ssrc[e] * NFW);
#pragma unroll
            for (int j = 0; j < 4; ++j) {
                int r2 = (nw + 4 * j) * 16 + l15;
                float own = acc1[mt][j][r2i];
                float oth = __shfl_xor(own, 1);
                union { unsigned int u; half2v h; } cv;
                cv.u = *(const unsigned int*)(nfrow + (r2 & ~1) * 2);
                float br = (float)cv.h[0], bi = (float)cv.h[1];
                float z = odd ? (br * own - bi * oth) : (br * own + bi * oth);
                int ksz = r2 >> 5;
                int off = (tm * 8 + ksz) * 1024 +
                          ((((((r2 >> 3) & 3) << 4) | (e & 15)) * 16) ^ (ksz << 4)) +
                          (r2 & 7) * 2;
                *(unsigned short*)((char*)Z + off) = f2hu(z);
            }
        }
    }
    __syncthreads();

    // GEMM2: msg = Z @ Chat (K = 256) + Nyquist rank-1
    f32x4 acc2[2][4] = {};
#pragma unroll
    for (int ks = 0; ks < 8; ++ks) {
        half8 a0 = *(const half8*)((char*)Z + ((2 * mw + 0) * 8 + ks) * 1024 + ((lane * 16) ^ (ks << 4)));
        half8 a1 = *(const half8*)((char*)Z + ((2 * mw + 1) * 8 + ks) * 1024 + ((lane * 16) ^ (ks << 4)));
#pragma unroll
        for (int j = 0; j < 4; ++j) {
            half8 bf = *(const half8*)(g_CB + ((size_t)(ks * 16 + 4 * nw + j) * 64 + lane) * 8);
            acc2[0][j] = MFMA16F(a0, bf, acc2[0][j], 0, 0, 0);
            acc2[1][j] = MFMA16F(a1, bf, acc2[1][j], 0, 0, 0);
        }
    }
    {
        float c256[4];
#pragma unroll
        for (int j = 0; j < 4; ++j) c256[j] = g_C256[(4 * nw + j) * 16 + l15];
#pragma unroll
        for (int mt = 0; mt < 2; ++mt)
#pragma unroll
            for (int r2i = 0; r2i < 4; ++r2i) {
                float zn = nyq[(2 * mw + mt) * 16 + lg * 4 + r2i];
#pragma unroll
                for (int j = 0; j < 4; ++j)
                    acc2[mt][j][r2i] = fmaf(zn, c256[j], acc2[mt][j][r2i]);
            }
    }

    // scatter: norm-scaled, dst-run compressed (sorted order)
#pragma unroll
    for (int mt = 0; mt < 2; ++mt) {
        const int e0 = (2 * mw + mt) * 16 + lg * 4;
        const bool v0 = ebase + e0 < E, v1 = ebase + e0 + 1 < E;
        const bool v2 = ebase + e0 + 2 < E, v3 = ebase + e0 + 3 < E;
        const int d0 = sdd[e0], d1 = sdd[e0 + 1], d2 = sdd[e0 + 2], d3 = sdd[e0 + 3];
        const float n0 = snrm[e0], n1 = snrm[e0 + 1], n2 = snrm[e0 + 2], n3 = snrm[e0 + 3];
        const bool uni = v3 && (d0 == d1) && (d1 == d2) && (d2 == d3);
        const bool p01 = v1 && (d0 == d1);
        const bool p23 = v3 && (d2 == d3);
#pragma unroll
        for (int j = 0; j < 4; ++j) {
            const int col = (4 * nw + j) * 16 + l15;
            float x0 = acc2[mt][j][0] * n0, x1 = acc2[mt][j][1] * n1;
            float x2 = acc2[mt][j][2] * n2, x3 = acc2[mt][j][3] * n3;
            if (uni) {
                atomAddF(agg + (long long)d0 * 256 + col, (x0 + x1) + (x2 + x3));
            } else {
                if (p01) atomAddF(agg + (long long)d0 * 256 + col, x0 + x1);
                else {
                    if (v0) atomAddF(agg + (long long)d0 * 256 + col, x0);
                    if (v1) atomAddF(agg + (long long)d1 * 256 + col, x1);
                }
                if (p23) atomAddF(agg + (long long)d2 * 256 + col, x2 + x3);
                else {
                    if (v2) atomAddF(agg + (long long)d2 * 256 + col, x2);
                    if (v3) atomAddF(agg + (long long)d3 * 256 + col, x3);
                }
            }
        }
    }
}

// ---------------------------------------------------------------------------
// stats: per-column sum / sumsq of h (= d_out) for BN
// ---------------------------------------------------------------------------
__global__ __launch_bounds__(256) void stats_kernel(
    const float* __restrict__ h, float* __restrict__ s1g,
    float* __restrict__ s2g, long long tot4) {
    __shared__ float s1l[256], s2l[256];
    const int t = threadIdx.x;
    s1l[t] = 0.f;
    s2l[t] = 0.f;
    __syncthreads();
    const int dg = t & 63;
    float a1[4] = {0.f, 0.f, 0.f, 0.f}, a2[4] = {0.f, 0.f, 0.f, 0.f};
    const long long stride = (long long)gridDim.x * 256;
    for (long long i4 = (long long)blockIdx.x * 256 + t; i4 < tot4; i4 += stride) {
        float4 v = ((const float4*)h)[i4];
        a1[0] += v.x; a2[0] += v.x * v.x;
        a1[1] += v.y; a2[1] += v.y * v.y;
        a1[2] += v.z; a2[2] += v.z * v.z;
        a1[3] += v.w; a2[3] += v.w * v.w;
    }
#pragma unroll
    for (int c = 0; c < 4; ++c) {
        atomicAdd(&s1l[dg * 4 + c], a1[c]);
        atomicAdd(&s2l[dg * 4 + c], a2[c]);
    }
    __syncthreads();
    atomAddF(&s1g[t], s1l[t]);
    atomAddF(&s2g[t], s2l[t]);
}

// ---------------------------------------------------------------------------
// finalize: out = tanh((h - mean) * rsqrt(var + eps) * gamma + beta)
// ---------------------------------------------------------------------------
__global__ __launch_bounds__(256) void finalize_kernel(
    float* __restrict__ out, const float* __restrict__ s1g,
    const float* __restrict__ s2g, const float* __restrict__ gamma,
    const float* __restrict__ beta, int N) {
    long long i4 = (long long)blockIdx.x * blockDim.x + threadIdx.x;
    long long tot = (long long)N * 64;
    if (i4 >= tot) return;
    const int dg = (int)(i4 & 63);
    float4 h = ((float4*)out)[i4];
    const float4 s1 = ((const float4*)s1g)[dg];
    const float4 s2 = ((const float4*)s2g)[dg];
    const float4 g = ((const float4*)gamma)[dg];
    const float4 b = ((const float4*)beta)[dg];
    const float invN = 1.f / (float)N;
    float4 o;
    { float m = s1.x * invN; float v = s2.x * invN - m * m;
      o.x = tanhf(fmaf(h.x - m, rsqrtf(v + BN_EPS) * g.x, b.x)); }
    { float m = s1.y * invN; float v = s2.y * invN - m * m;
      o.y = tanhf(fmaf(h.y - m, rsqrtf(v + BN_EPS) * g.y, b.y)); }
    { float m = s1.z * invN; float v = s2.z * invN - m * m;
      o.z = tanhf(fmaf(h.z - m, rsqrtf(v + BN_EPS) * g.z, b.z)); }
    { float m = s1.w * invN; float v = s2.w * invN - m * m;
      o.w = tanhf(fmaf(h.w - m, rsqrtf(v + BN_EPS) * g.w, b.w)); }
    ((float4*)out)[i4] = o;
}

// ---------------------------------------------------------------------------
extern "C" void kernel_launch(void* const* d_in, const int* in_sizes, int n_in,
                              void* d_out, int out_size, void* d_ws, size_t ws_size,
                              hipStream_t stream) {
    const float* node_ft  = (const float*)d_in[0];
    const float* edge_ft  = (const float*)d_in[1];
    const float* norm     = (const float*)d_in[2];
    const float* w_loop   = (const float*)d_in[3];
    const float* w_in     = (const float*)d_in[4];
    const float* loop_rel = (const float*)d_in[5];
    const float* w_bias   = (const float*)d_in[6];
    const float* bn_gamma = (const float*)d_in[7];
    const float* bn_beta  = (const float*)d_in[8];
    const int*   src      = (const int*)d_in[9];
    const int*   dst      = (const int*)d_in[10];

    const int N = in_sizes[2];
    const int E = in_sizes[9];
    float* out = (float*)d_out;

    float* s1g = (float*)d_ws;
    float* s2g = s1g + 256;

    hipMemsetAsync(d_ws, 0, 512 * sizeof(float), stream);

    float* Wle_ptr = nullptr;
    hipGetSymbolAddress((void**)&Wle_ptr, HIP_SYMBOL(g_Wle));
    void* hist_ptr = nullptr;
    hipGetSymbolAddress(&hist_ptr, HIP_SYMBOL(g_hist));
    hipMemsetAsync(hist_ptr, 0, (size_t)N * sizeof(int), stream);

    const int sblk = (N + 511) / 512;
    const int eblk = (E + 511) / 512;

    // dst counting sort -> g_perm
    hist_kernel<<<eblk, 512, 0, stream>>>(dst, E);
    scanA_kernel<<<sblk, 512, 0, stream>>>(N);
    scanB_kernel<<<1, 128, 0, stream>>>(sblk);
    scanC_kernel<<<sblk, 512, 0, stream>>>(N);
    perm_kernel<<<eblk, 512, 0, stream>>>(dst, E);

    // constant packs
    wle_kernel<<<256, 256, 0, stream>>>(loop_rel, w_loop, Wle_ptr);
    fb_pack<<<8 * 20, 512, 0, stream>>>();
    cb_pack<<<9 * 16, 512, 0, stream>>>(w_in);
    wleb_pack<<<8 * 16, 512, 0, stream>>>();

    // node pass -> NF + (loop_msg + bias) in d_out
    nfloop_kernel<<<(N + 63) / 64, 512, 0, stream>>>(node_ft, w_bias, out, N);
    // fused edge pass, XCD-chunked over dst-sorted tiles, 2 blocks/CU
    edge_kernel<<<(E + 63) / 64, 512, 0, stream>>>(edge_ft, norm, src, dst, out, E);
    stats_kernel<<<1024, 256, 0, stream>>>(out, s1g, s2g, (long long)N * 64);
    finalize_kernel<<<(int)(((long long)N * 64 + 255) / 256), 256, 0, stream>>>(
        out, s1g, s2g, bn_gamma, bn_beta, N);
}